// Round 1
// baseline (15081.853 us; speedup 1.0000x reference)
//
#include <hip/hip_runtime.h>

// LSTM B=32 T=2048 I=H=512. out = h_T [1,32,512] f32.
// Phase 1 (lstm_p1): x_proj chunk GEMM (bf16 MFMA), xp[t_local][b][4H] bf16 in ws.
// Phase 2 (lstm_p2): persistent recurrence, 32 blocks; block k owns hidden units
//   [16k,16k+16) (64 gate rows). W_hh fragments in registers; per-step H exchange
//   via global ping-pong + device-scope counter barrier.

#define T_FULL 2048
#define CHUNK  256
#define NCHUNK 8
#define NBLK   32

typedef float  f32x4 __attribute__((ext_vector_type(4)));
typedef short  s16x8 __attribute__((ext_vector_type(8)));

#define MFMA16(a,b,c) __builtin_amdgcn_mfma_f32_16x16x32_bf16((a),(b),(c),0,0,0)

__device__ inline unsigned short f2bf(float f){
  unsigned u = __builtin_bit_cast(unsigned, f);
  u += 0x7fffu + ((u>>16)&1u);          // RNE
  return (unsigned short)(u>>16);
}
__device__ inline float bf2f(unsigned short s){
  unsigned u = ((unsigned)s)<<16;
  return __builtin_bit_cast(float, u);
}
__device__ inline float sigmoid_(float x){
  x = fminf(fmaxf(x,-30.f),30.f);
  return 1.f/(1.f + __expf(-x));
}
__device__ inline float tanh_(float x){
  x = fminf(fmaxf(x,-15.f),15.f);
  float e = __expf(2.f*x);
  return (e-1.f)/(e+1.f);
}

// ---------------- Phase 1: x_proj chunk GEMM ----------------
// grid (32, CHUNK*32/64): block tile 64(M) x 64(N), K=512 in 4 rounds of 128.
// M index m (chunk-local) -> t = t0 + m>>5, b = m&31. Output xp[m][n] bf16.
__global__ __launch_bounds__(256) void lstm_p1(
    const float* __restrict__ x, const float* __restrict__ Wih,
    const float* __restrict__ bih, const float* __restrict__ bhh,
    unsigned short* __restrict__ xp, int t0)
{
  __shared__ __align__(16) unsigned short At[64*136];
  __shared__ __align__(16) unsigned short Bt[64*136];
  const int tid = threadIdx.x, lane = tid&63, w = tid>>6;
  const int l15 = lane&15, l4 = lane>>4;
  const int n0 = blockIdx.x*64, m0 = blockIdx.y*64;
  const int mbase = (w&1)*32, nbase = (w>>1)*32;

  f32x4 acc[2][2];
  #pragma unroll
  for (int mi=0; mi<2; ++mi)
    #pragma unroll
    for (int ni=0; ni<2; ++ni)
      acc[mi][ni] = (f32x4){0.f,0.f,0.f,0.f};

  for (int kb=0; kb<4; ++kb){
    #pragma unroll
    for (int it=0; it<4; ++it){
      int grp = it*256 + tid;            // 0..1023
      int row = grp>>4, c8 = (grp&15)*8; // 16 groups of 8 per row
      {
        int m = m0 + row;
        size_t t = (size_t)t0 + (m>>5), b = (size_t)(m&31);
        const float* src = x + ((b*2048 + t)<<9) + kb*128 + c8;
        f32x4 v0 = *(const f32x4*)src, v1 = *(const f32x4*)(src+4);
        unsigned short* d = &At[row*136 + c8];
        d[0]=f2bf(v0[0]); d[1]=f2bf(v0[1]); d[2]=f2bf(v0[2]); d[3]=f2bf(v0[3]);
        d[4]=f2bf(v1[0]); d[5]=f2bf(v1[1]); d[6]=f2bf(v1[2]); d[7]=f2bf(v1[3]);
      }
      {
        const float* src = Wih + (size_t)(n0+row)*512 + kb*128 + c8;
        f32x4 v0 = *(const f32x4*)src, v1 = *(const f32x4*)(src+4);
        unsigned short* d = &Bt[row*136 + c8];
        d[0]=f2bf(v0[0]); d[1]=f2bf(v0[1]); d[2]=f2bf(v0[2]); d[3]=f2bf(v0[3]);
        d[4]=f2bf(v1[0]); d[5]=f2bf(v1[1]); d[6]=f2bf(v1[2]); d[7]=f2bf(v1[3]);
      }
    }
    __syncthreads();
    #pragma unroll
    for (int ks=0; ks<4; ++ks){
      s16x8 af0 = *(const s16x8*)&At[(mbase+   l15)*136 + ks*32 + l4*8];
      s16x8 af1 = *(const s16x8*)&At[(mbase+16+l15)*136 + ks*32 + l4*8];
      s16x8 bf0 = *(const s16x8*)&Bt[(nbase+   l15)*136 + ks*32 + l4*8];
      s16x8 bf1 = *(const s16x8*)&Bt[(nbase+16+l15)*136 + ks*32 + l4*8];
      acc[0][0] = MFMA16(af0,bf0,acc[0][0]);
      acc[0][1] = MFMA16(af0,bf1,acc[0][1]);
      acc[1][0] = MFMA16(af1,bf0,acc[1][0]);
      acc[1][1] = MFMA16(af1,bf1,acc[1][1]);
    }
    __syncthreads();
  }
  #pragma unroll
  for (int ni=0; ni<2; ++ni){
    int col = n0 + nbase + ni*16 + l15;
    float bias = bih[col] + bhh[col];
    #pragma unroll
    for (int mi=0; mi<2; ++mi){
      #pragma unroll
      for (int r=0; r<4; ++r){
        int mrow = m0 + mbase + mi*16 + l4*4 + r;
        xp[(size_t)mrow*2048 + col] = f2bf(acc[mi][ni][r] + bias);
      }
    }
  }
}

// ---------------- Phase 2: recurrence ----------------
// 32 blocks x 256 threads. Block k owns units [16k,16k+16).
// Hbuf: 2 slots [32][512] bf16 (linear). LDS Hl: XOR-swizzled copy (byte^=((row&7)<<4)).
// bar[t]: arrivals for step t. wf: 2 N-tiles x 16 k-steps of B-fragments in VGPRs.
__global__ __launch_bounds__(256) void lstm_p2(
    const unsigned short* __restrict__ xp, const float* __restrict__ Whh,
    unsigned short* __restrict__ Hbuf, float* __restrict__ cst,
    unsigned int* __restrict__ bar, float* __restrict__ out, int t0)
{
  const int k = blockIdx.x;
  const int tid = threadIdx.x;
  const int lane = tid & 63, w = tid >> 6;
  const int l15 = lane & 15, l4 = lane >> 4;
  const int mt = w & 1, gp = w >> 1;

  __shared__ __align__(16) char Hl[32*1024];
  __shared__ float zl[32][68];

  // Preload W_hh fragments (bf16) into registers: wf[nt][ks]
  s16x8 wf[2][16];
  #pragma unroll
  for (int nt=0; nt<2; ++nt){
    int lrow = gp*32 + nt*16 + l15;                       // 0..63 local gate row
    int grow = (lrow>>4)*512 + k*16 + (lrow&15);          // global gate row
    const float* wr = Whh + (size_t)grow*512;
    #pragma unroll
    for (int ks=0; ks<16; ++ks){
      const float* s = wr + ks*32 + l4*8;
      f32x4 v0 = *(const f32x4*)s, v1 = *(const f32x4*)(s+4);
      s16x8 tt;
      tt[0]=(short)f2bf(v0[0]); tt[1]=(short)f2bf(v0[1]);
      tt[2]=(short)f2bf(v0[2]); tt[3]=(short)f2bf(v0[3]);
      tt[4]=(short)f2bf(v1[0]); tt[5]=(short)f2bf(v1[1]);
      tt[6]=(short)f2bf(v1[2]); tt[7]=(short)f2bf(v1[3]);
      wf[nt][ks] = tt;
    }
  }

  const int s_ = tid >> 3, a_ = tid & 7;    // seq, unit-pair index
  const int ucol = k*16 + 2*a_;             // global hidden col of first unit
  float c0 = cst[s_*512 + ucol], c1 = cst[s_*512 + ucol + 1];

  for (int tt=0; tt<CHUNK; ++tt){
    const int t = t0 + tt;

    // prefetch xp for this thread's 2 units x 4 gates (independent of barrier)
    unsigned int xq[4];
    #pragma unroll
    for (int g=0; g<4; ++g)
      xq[g] = *(const unsigned int*)(xp + (size_t)(tt*32 + s_)*2048 + g*512 + ucol);

    if (t > 0){
      if (tid == 0){
        while (__hip_atomic_load(&bar[t-1], __ATOMIC_ACQUIRE, __HIP_MEMORY_SCOPE_AGENT) < NBLK)
          __builtin_amdgcn_s_sleep(1);
      }
      __syncthreads();
    }

    // stage H_{t-1} (slot (t-1)&1) into swizzled LDS
    {
      const char* hsrc = (const char*)(Hbuf + ((t+1)&1)*(32*512));
      #pragma unroll
      for (int it=0; it<8; ++it){
        int off = (it*256 + tid)*16;        // 0..32K
        f32x4 v = *(const f32x4*)(hsrc + off);
        *(f32x4*)&Hl[off ^ (((off>>10)&7)<<4)] = v;
      }
    }
    __syncthreads();

    // z-slice = H @ Wslice^T
    f32x4 acc0 = (f32x4){0.f,0.f,0.f,0.f};
    f32x4 acc1 = (f32x4){0.f,0.f,0.f,0.f};
    {
      const int row = mt*16 + l15;
      const int swz = (row&7)<<4;
      const int rbase = row<<10;
      #pragma unroll
      for (int ks=0; ks<16; ++ks){
        int cb = ks*64 + l4*16;
        s16x8 af = *(const s16x8*)&Hl[rbase | (cb ^ swz)];
        acc0 = MFMA16(af, wf[0][ks], acc0);
        acc1 = MFMA16(af, wf[1][ks], acc1);
      }
    }
    #pragma unroll
    for (int r=0; r<4; ++r){
      zl[mt*16 + l4*4 + r][gp*32 +      l15] = acc0[r];
      zl[mt*16 + l4*4 + r][gp*32 + 16 + l15] = acc1[r];
    }
    __syncthreads();

    // gates for (s_, units 2a_ and 2a_+1)
    float zi0 = zl[s_][ 0 + 2*a_    ] + bf2f((unsigned short)(xq[0]&0xffffu));
    float zi1 = zl[s_][ 0 + 2*a_ + 1] + bf2f((unsigned short)(xq[0]>>16));
    float zf0 = zl[s_][16 + 2*a_    ] + bf2f((unsigned short)(xq[1]&0xffffu));
    float zf1 = zl[s_][16 + 2*a_ + 1] + bf2f((unsigned short)(xq[1]>>16));
    float zg0 = zl[s_][32 + 2*a_    ] + bf2f((unsigned short)(xq[2]&0xffffu));
    float zg1 = zl[s_][32 + 2*a_ + 1] + bf2f((unsigned short)(xq[2]>>16));
    float zo0 = zl[s_][48 + 2*a_    ] + bf2f((unsigned short)(xq[3]&0xffffu));
    float zo1 = zl[s_][48 + 2*a_ + 1] + bf2f((unsigned short)(xq[3]>>16));

    float i0 = sigmoid_(zi0), f0 = sigmoid_(zf0), g0 = tanh_(zg0), o0 = sigmoid_(zo0);
    float i1 = sigmoid_(zi1), f1 = sigmoid_(zf1), g1 = tanh_(zg1), o1 = sigmoid_(zo1);
    c0 = f0*c0 + i0*g0;
    c1 = f1*c1 + i1*g1;
    float h0 = o0 * tanh_(c0);
    float h1 = o1 * tanh_(c1);

    // write h to slot t&1 (linear layout)
    {
      unsigned short* hdst = Hbuf + (t&1)*(32*512);
      unsigned int hp = (unsigned int)f2bf(h0) | ((unsigned int)f2bf(h1)<<16);
      *(unsigned int*)((char*)hdst + s_*1024 + ucol*2) = hp;
    }
    if (t == T_FULL-1){
      out[s_*512 + ucol    ] = h0;
      out[s_*512 + ucol + 1] = h1;
    }

    __threadfence();
    __syncthreads();
    if (tid == 0)
      __hip_atomic_fetch_add(&bar[t], 1u, __ATOMIC_RELEASE, __HIP_MEMORY_SCOPE_AGENT);
  }

  cst[s_*512 + ucol    ] = c0;
  cst[s_*512 + ucol + 1] = c1;
}

// ---------------- launch ----------------
extern "C" void kernel_launch(void* const* d_in, const int* in_sizes, int n_in,
                              void* d_out, int out_size, void* d_ws, size_t ws_size,
                              hipStream_t stream)
{
  const float* x   = (const float*)d_in[0];
  const float* Wih = (const float*)d_in[1];
  const float* Whh = (const float*)d_in[2];
  const float* bih = (const float*)d_in[3];
  const float* bhh = (const float*)d_in[4];
  float* out = (float*)d_out;

  char* ws = (char*)d_ws;
  const size_t XP_BYTES = (size_t)CHUNK*32*2048*2;     // 33,554,432
  unsigned short* xp   = (unsigned short*)ws;
  unsigned short* Hbuf = (unsigned short*)(ws + XP_BYTES);          // 2*32*512*2 = 65536
  float*          cst  = (float*)(ws + XP_BYTES + 65536);           // 32*512*4   = 65536
  unsigned int*   bar  = (unsigned int*)(ws + XP_BYTES + 131072);   // 2048*4     = 8192

  // zero Hbuf + cstate + barrier counters (re-done every call: deterministic)
  hipMemsetAsync(Hbuf, 0, 65536 + 65536 + 8192, stream);

  for (int c=0; c<NCHUNK; ++c){
    int t0 = c*CHUNK;
    lstm_p1<<<dim3(32, CHUNK*32/64), 256, 0, stream>>>(x, Wih, bih, bhh, xp, t0);
    lstm_p2<<<NBLK, 256, 0, stream>>>(xp, Whh, Hbuf, cst, bar, out, t0);
  }
}

// Round 3
// 6381.923 us; speedup vs baseline: 2.3632x; 2.3632x over previous
//
#include <hip/hip_runtime.h>

// LSTM B=32 T=2048 I=H=512. out = h_T [1,32,512] f32.
// Phase 1 (lstm_p1): x_proj chunk GEMM (bf16 MFMA), xp[t_local][b][4H] bf16 in ws.
// Phase 2 (lstm_p2): persistent recurrence, 32 blocks; block k owns hidden units
//   [16k,16k+16) (64 gate rows). W_hh fragments in registers; per-step H exchange
//   via global ping-pong + per-block flags (relaxed sc1 traffic, one acquire/step).

#define T_FULL 2048
#define CHUNK  256
#define NCHUNK 8
#define NBLK   32

typedef float  f32x4 __attribute__((ext_vector_type(4)));
typedef short  s16x8 __attribute__((ext_vector_type(8)));

#define MFMA16(a,b,c) __builtin_amdgcn_mfma_f32_16x16x32_bf16((a),(b),(c),0,0,0)

__device__ inline unsigned short f2bf(float f){
  unsigned u = __builtin_bit_cast(unsigned, f);
  u += 0x7fffu + ((u>>16)&1u);          // RNE
  return (unsigned short)(u>>16);
}
__device__ inline float bf2f(unsigned short s){
  unsigned u = ((unsigned)s)<<16;
  return __builtin_bit_cast(float, u);
}
__device__ inline float sigmoid_(float x){
  x = fminf(fmaxf(x,-30.f),30.f);
  return 1.f/(1.f + __expf(-x));
}
__device__ inline float tanh_(float x){
  x = fminf(fmaxf(x,-15.f),15.f);
  float e = __expf(2.f*x);
  return (e-1.f)/(e+1.f);
}

// ---------------- Phase 1: x_proj chunk GEMM ----------------
__global__ __launch_bounds__(256) void lstm_p1(
    const float* __restrict__ x, const float* __restrict__ Wih,
    const float* __restrict__ bih, const float* __restrict__ bhh,
    unsigned short* __restrict__ xp, int t0)
{
  __shared__ __align__(16) unsigned short At[64*136];
  __shared__ __align__(16) unsigned short Bt[64*136];
  const int tid = threadIdx.x, lane = tid&63, w = tid>>6;
  const int l15 = lane&15, l4 = lane>>4;
  const int n0 = blockIdx.x*64, m0 = blockIdx.y*64;
  const int mbase = (w&1)*32, nbase = (w>>1)*32;

  f32x4 acc[2][2];
  #pragma unroll
  for (int mi=0; mi<2; ++mi)
    #pragma unroll
    for (int ni=0; ni<2; ++ni)
      acc[mi][ni] = (f32x4){0.f,0.f,0.f,0.f};

  for (int kb=0; kb<4; ++kb){
    #pragma unroll
    for (int it=0; it<4; ++it){
      int grp = it*256 + tid;            // 0..1023
      int row = grp>>4, c8 = (grp&15)*8; // 16 groups of 8 per row
      {
        int m = m0 + row;
        size_t t = (size_t)t0 + (m>>5), b = (size_t)(m&31);
        const float* src = x + ((b*2048 + t)<<9) + kb*128 + c8;
        f32x4 v0 = *(const f32x4*)src, v1 = *(const f32x4*)(src+4);
        unsigned short* d = &At[row*136 + c8];
        d[0]=f2bf(v0[0]); d[1]=f2bf(v0[1]); d[2]=f2bf(v0[2]); d[3]=f2bf(v0[3]);
        d[4]=f2bf(v1[0]); d[5]=f2bf(v1[1]); d[6]=f2bf(v1[2]); d[7]=f2bf(v1[3]);
      }
      {
        const float* src = Wih + (size_t)(n0+row)*512 + kb*128 + c8;
        f32x4 v0 = *(const f32x4*)src, v1 = *(const f32x4*)(src+4);
        unsigned short* d = &Bt[row*136 + c8];
        d[0]=f2bf(v0[0]); d[1]=f2bf(v0[1]); d[2]=f2bf(v0[2]); d[3]=f2bf(v0[3]);
        d[4]=f2bf(v1[0]); d[5]=f2bf(v1[1]); d[6]=f2bf(v1[2]); d[7]=f2bf(v1[3]);
      }
    }
    __syncthreads();
    #pragma unroll
    for (int ks=0; ks<4; ++ks){
      s16x8 af0 = *(const s16x8*)&At[(mbase+   l15)*136 + ks*32 + l4*8];
      s16x8 af1 = *(const s16x8*)&At[(mbase+16+l15)*136 + ks*32 + l4*8];
      s16x8 bf0 = *(const s16x8*)&Bt[(nbase+   l15)*136 + ks*32 + l4*8];
      s16x8 bf1 = *(const s16x8*)&Bt[(nbase+16+l15)*136 + ks*32 + l4*8];
      acc[0][0] = MFMA16(af0,bf0,acc[0][0]);
      acc[0][1] = MFMA16(af0,bf1,acc[0][1]);
      acc[1][0] = MFMA16(af1,bf0,acc[1][0]);
      acc[1][1] = MFMA16(af1,bf1,acc[1][1]);
    }
    __syncthreads();
  }
  #pragma unroll
  for (int ni=0; ni<2; ++ni){
    int col = n0 + nbase + ni*16 + l15;
    float bias = bih[col] + bhh[col];
    #pragma unroll
    for (int mi=0; mi<2; ++mi){
      #pragma unroll
      for (int r=0; r<4; ++r){
        int mrow = m0 + mbase + mi*16 + l4*4 + r;
        xp[(size_t)mrow*2048 + col] = f2bf(acc[mi][ni][r] + bias);
      }
    }
  }
}

// ---------------- Phase 2: recurrence ----------------
// flags: flag[k*32] (128B apart), value = latest step published by block k (t+1).
// Producer: relaxed sc1 atomic h-stores -> vmcnt(0)+barrier -> relaxed flag store.
// Consumer: wave0 lanes 0..31 poll all flags relaxed; ONE acquire fence (buffer_inv);
//           then normal vectorized H loads into swizzled LDS.
__global__ __launch_bounds__(256) void lstm_p2(
    const unsigned short* __restrict__ xp, const float* __restrict__ Whh,
    unsigned short* __restrict__ Hbuf, float* __restrict__ cst,
    unsigned int* __restrict__ flag, float* __restrict__ out, int t0)
{
  const int k = blockIdx.x;
  const int tid = threadIdx.x;
  const int lane = tid & 63, w = tid >> 6;
  const int l15 = lane & 15, l4 = lane >> 4;
  const int mt = w & 1, gp = w >> 1;

  __shared__ __align__(16) char Hl[32*1024];
  __shared__ float zl[32][68];

  // Preload W_hh fragments (bf16) into registers: wf[nt][ks]
  s16x8 wf[2][16];
  #pragma unroll
  for (int nt=0; nt<2; ++nt){
    int lrow = gp*32 + nt*16 + l15;                       // 0..63 local gate row
    int grow = (lrow>>4)*512 + k*16 + (lrow&15);          // global gate row
    const float* wr = Whh + (size_t)grow*512;
    #pragma unroll
    for (int ks=0; ks<16; ++ks){
      const float* s = wr + ks*32 + l4*8;
      f32x4 v0 = *(const f32x4*)s, v1 = *(const f32x4*)(s+4);
      s16x8 tt;
      tt[0]=(short)f2bf(v0[0]); tt[1]=(short)f2bf(v0[1]);
      tt[2]=(short)f2bf(v0[2]); tt[3]=(short)f2bf(v0[3]);
      tt[4]=(short)f2bf(v1[0]); tt[5]=(short)f2bf(v1[1]);
      tt[6]=(short)f2bf(v1[2]); tt[7]=(short)f2bf(v1[3]);
      wf[nt][ks] = tt;
    }
  }

  const int s_ = tid >> 3, a_ = tid & 7;    // seq, unit-pair index
  const int ucol = k*16 + 2*a_;             // global hidden col of first unit
  float c0 = cst[s_*512 + ucol], c1 = cst[s_*512 + ucol + 1];

  for (int tt=0; tt<CHUNK; ++tt){
    const int t = t0 + tt;

    // prefetch xp for this thread's 2 units x 4 gates (independent of barrier)
    unsigned int xq[4];
    #pragma unroll
    for (int g=0; g<4; ++g)
      xq[g] = *(const unsigned int*)(xp + (size_t)(tt*32 + s_)*2048 + g*512 + ucol);

    if (t > 0){
      if (w == 0){
        unsigned v;
        do {
          v = (lane < NBLK)
            ? __hip_atomic_load(&flag[lane<<5], __ATOMIC_RELAXED, __HIP_MEMORY_SCOPE_AGENT)
            : 0xffffffffu;
        } while (!__all(v >= (unsigned)t));
        __builtin_amdgcn_fence(__ATOMIC_ACQUIRE, "agent");
      }
      __syncthreads();
    }

    // stage H_{t-1} (slot (t-1)&1) into swizzled LDS
    {
      const char* hsrc = (const char*)(Hbuf + ((t+1)&1)*(32*512));
      #pragma unroll
      for (int it=0; it<8; ++it){
        int off = (it*256 + tid)*16;        // 0..32K
        f32x4 v = *(const f32x4*)(hsrc + off);
        *(f32x4*)&Hl[off ^ (((off>>10)&7)<<4)] = v;
      }
    }
    __syncthreads();

    // z-slice = H @ Wslice^T
    f32x4 acc0 = (f32x4){0.f,0.f,0.f,0.f};
    f32x4 acc1 = (f32x4){0.f,0.f,0.f,0.f};
    {
      const int row = mt*16 + l15;
      const int swz = (row&7)<<4;
      const int rbase = row<<10;
      #pragma unroll
      for (int ks=0; ks<16; ++ks){
        int cb = ks*64 + l4*16;
        s16x8 af = *(const s16x8*)&Hl[rbase | (cb ^ swz)];
        acc0 = MFMA16(af, wf[0][ks], acc0);
        acc1 = MFMA16(af, wf[1][ks], acc1);
      }
    }
    #pragma unroll
    for (int r=0; r<4; ++r){
      zl[mt*16 + l4*4 + r][gp*32 +      l15] = acc0[r];
      zl[mt*16 + l4*4 + r][gp*32 + 16 + l15] = acc1[r];
    }
    __syncthreads();

    // gates for (s_, units 2a_ and 2a_+1)
    float zi0 = zl[s_][ 0 + 2*a_    ] + bf2f((unsigned short)(xq[0]&0xffffu));
    float zi1 = zl[s_][ 0 + 2*a_ + 1] + bf2f((unsigned short)(xq[0]>>16));
    float zf0 = zl[s_][16 + 2*a_    ] + bf2f((unsigned short)(xq[1]&0xffffu));
    float zf1 = zl[s_][16 + 2*a_ + 1] + bf2f((unsigned short)(xq[1]>>16));
    float zg0 = zl[s_][32 + 2*a_    ] + bf2f((unsigned short)(xq[2]&0xffffu));
    float zg1 = zl[s_][32 + 2*a_ + 1] + bf2f((unsigned short)(xq[2]>>16));
    float zo0 = zl[s_][48 + 2*a_    ] + bf2f((unsigned short)(xq[3]&0xffffu));
    float zo1 = zl[s_][48 + 2*a_ + 1] + bf2f((unsigned short)(xq[3]>>16));

    float i0 = sigmoid_(zi0), f0 = sigmoid_(zf0), g0 = tanh_(zg0), o0 = sigmoid_(zo0);
    float i1 = sigmoid_(zi1), f1 = sigmoid_(zf1), g1 = tanh_(zg1), o1 = sigmoid_(zo1);
    c0 = f0*c0 + i0*g0;
    c1 = f1*c1 + i1*g1;
    float h0 = o0 * tanh_(c0);
    float h1 = o1 * tanh_(c1);

    // publish h (slot t&1): relaxed agent atomics -> write-through, no dirty L2
    {
      unsigned short* hdst = Hbuf + (t&1)*(32*512);
      unsigned int hp = (unsigned int)f2bf(h0) | ((unsigned int)f2bf(h1)<<16);
      __hip_atomic_store((unsigned int*)((char*)hdst + s_*1024 + ucol*2), hp,
                         __ATOMIC_RELAXED, __HIP_MEMORY_SCOPE_AGENT);
    }
    if (t == T_FULL-1){
      out[s_*512 + ucol    ] = h0;
      out[s_*512 + ucol + 1] = h1;
    }

    // drain our stores (global visibility for sc1 write-through), block-wide
    asm volatile("s_waitcnt vmcnt(0)" ::: "memory");
    __syncthreads();
    if (tid == 0)
      __hip_atomic_store(&flag[k<<5], (unsigned)(t+1),
                         __ATOMIC_RELAXED, __HIP_MEMORY_SCOPE_AGENT);
  }

  cst[s_*512 + ucol    ] = c0;
  cst[s_*512 + ucol + 1] = c1;
}

// ---------------- launch ----------------
extern "C" void kernel_launch(void* const* d_in, const int* in_sizes, int n_in,
                              void* d_out, int out_size, void* d_ws, size_t ws_size,
                              hipStream_t stream)
{
  const float* x   = (const float*)d_in[0];
  const float* Wih = (const float*)d_in[1];
  const float* Whh = (const float*)d_in[2];
  const float* bih = (const float*)d_in[3];
  const float* bhh = (const float*)d_in[4];
  float* out = (float*)d_out;

  char* ws = (char*)d_ws;
  const size_t XP_BYTES = (size_t)CHUNK*32*2048*2;     // 33,554,432
  unsigned short* xp   = (unsigned short*)ws;
  unsigned short* Hbuf = (unsigned short*)(ws + XP_BYTES);          // 2*32*512*2 = 65536
  float*          cst  = (float*)(ws + XP_BYTES + 65536);           // 32*512*4   = 65536
  unsigned int*   flag = (unsigned int*)(ws + XP_BYTES + 131072);   // 32*128B    = 4096

  // zero Hbuf + cstate + flags (re-done every call: deterministic)
  (void)hipMemsetAsync(Hbuf, 0, 65536 + 65536 + 4096, stream);

  for (int c=0; c<NCHUNK; ++c){
    int t0 = c*CHUNK;
    lstm_p1<<<dim3(32, CHUNK*32/64), 256, 0, stream>>>(x, Wih, bih, bhh, xp, t0);
    lstm_p2<<<NBLK, 256, 0, stream>>>(xp, Whh, Hbuf, cst, flag, out, t0);
  }
}